// Round 1
// baseline (6621.404 us; speedup 1.0000x reference)
//
#include <hip/hip_runtime.h>
#include <math.h>

#define BLOCK 256
#define UNITS 32
#define IN_CH 10
#define STATS_BLOCKS 1024
#define PILLARS 30000
#define BN_EPS 1e-3f

// order-preserving float <-> uint map (handles negatives) for atomicMax
__device__ __forceinline__ unsigned int fmap(float f) {
    unsigned int u = __float_as_uint(f);
    return (u & 0x80000000u) ? ~u : (u | 0x80000000u);
}
__device__ __forceinline__ float funmap(unsigned int u) {
    unsigned int b = (u & 0x80000000u) ? (u & 0x7fffffffu) : ~u;
    return __uint_as_float(b);
}

// Pass 1: per-channel sum(x), sum(x^2) of the linear output, block partials
__global__ void __launch_bounds__(BLOCK) stats_kernel(const float* __restrict__ inp,
        const float* __restrict__ W, float* __restrict__ partials, int N) {
    __shared__ float Wl[UNITS * IN_CH];
    for (int i = threadIdx.x; i < UNITS * IN_CH; i += BLOCK) Wl[i] = W[i];
    __syncthreads();
    float acc[2 * UNITS];
#pragma unroll
    for (int i = 0; i < 2 * UNITS; i++) acc[i] = 0.f;
    int stride = gridDim.x * BLOCK;
    for (int row = blockIdx.x * BLOCK + threadIdx.x; row < N; row += stride) {
        float r[IN_CH];
        const float2* p2 = (const float2*)(inp + (size_t)row * IN_CH);
#pragma unroll
        for (int k = 0; k < IN_CH / 2; k++) { float2 v = p2[k]; r[2*k] = v.x; r[2*k+1] = v.y; }
#pragma unroll
        for (int u = 0; u < UNITS; u++) {
            float x = 0.f;
#pragma unroll
            for (int k = 0; k < IN_CH; k++) x = fmaf(r[k], Wl[u * IN_CH + k], x);
            acc[u] += x;
            acc[UNITS + u] = fmaf(x, x, acc[UNITS + u]);
        }
    }
    int lane = threadIdx.x & 63, wid = threadIdx.x >> 6;
    __shared__ float wpart[4][2 * UNITS];
#pragma unroll
    for (int k = 0; k < 2 * UNITS; k++) {
        float v = acc[k];
#pragma unroll
        for (int off = 32; off > 0; off >>= 1) v += __shfl_down(v, off, 64);
        if (lane == 0) wpart[wid][k] = v;
    }
    __syncthreads();
    if (threadIdx.x < 2 * UNITS) {
        float v = wpart[0][threadIdx.x] + wpart[1][threadIdx.x] +
                  wpart[2][threadIdx.x] + wpart[3][threadIdx.x];
        partials[blockIdx.x * (2 * UNITS) + threadIdx.x] = v;
    }
}

// Pass 2: fold mean/var/gamma/beta -> scale, bias
__global__ void __launch_bounds__(BLOCK) bn_finalize_kernel(const float* __restrict__ partials,
        const float* __restrict__ gamma, const float* __restrict__ beta,
        float* __restrict__ params, int nblocks, float invN) {
    int c = threadIdx.x & 63, q = threadIdx.x >> 6;
    float local = 0.f;
    for (int i = q; i < nblocks; i += 4) local += partials[i * 64 + c];
    __shared__ float s[4][64];
    __shared__ float tot[64];
    s[q][c] = local;
    __syncthreads();
    if (threadIdx.x < 64)
        tot[threadIdx.x] = s[0][threadIdx.x] + s[1][threadIdx.x] + s[2][threadIdx.x] + s[3][threadIdx.x];
    __syncthreads();
    if (threadIdx.x < UNITS) {
        int u = threadIdx.x;
        float mean = tot[u] * invN;
        float var = tot[UNITS + u] * invN - mean * mean;
        float scale = gamma[u] * rsqrtf(var + BN_EPS);
        params[u] = scale;
        params[UNITS + u] = beta[u] - mean * scale;
    }
}

// Pass 3: recompute x, BN+PReLU, write first half of out, pillar atomics
__global__ void __launch_bounds__(BLOCK) main_kernel(const float* __restrict__ inp,
        const float* __restrict__ W, const float* __restrict__ params,
        const float* __restrict__ prelu_a, const int* __restrict__ unq,
        float* __restrict__ out, float* __restrict__ sums,
        unsigned int* __restrict__ maxu, int* __restrict__ cnt, int N) {
    __shared__ float Wl[UNITS * IN_CH];
    __shared__ float sc[UNITS], bi[UNITS], pa[UNITS];
    for (int i = threadIdx.x; i < UNITS * IN_CH; i += BLOCK) Wl[i] = W[i];
    if (threadIdx.x < UNITS) {
        sc[threadIdx.x] = params[threadIdx.x];
        bi[threadIdx.x] = params[UNITS + threadIdx.x];
        pa[threadIdx.x] = prelu_a[threadIdx.x];
    }
    __syncthreads();
    int row = blockIdx.x * BLOCK + threadIdx.x;
    if (row >= N) return;
    float r[IN_CH];
    const float2* p2 = (const float2*)(inp + (size_t)row * IN_CH);
#pragma unroll
    for (int k = 0; k < IN_CH / 2; k++) { float2 v = p2[k]; r[2*k] = v.x; r[2*k+1] = v.y; }
    float y[UNITS];
#pragma unroll
    for (int u = 0; u < UNITS; u++) {
        float x = 0.f;
#pragma unroll
        for (int k = 0; k < IN_CH; k++) x = fmaf(r[k], Wl[u * IN_CH + k], x);
        x = fmaf(x, sc[u], bi[u]);
        y[u] = x > 0.f ? x : pa[u] * x;
    }
    float4* op = (float4*)(out + (size_t)row * 64);
#pragma unroll
    for (int g = 0; g < 8; g++)
        op[g] = make_float4(y[4*g], y[4*g+1], y[4*g+2], y[4*g+3]);
    int p = unq[row];
    atomicAdd(&cnt[p], 1);
    int base = p * UNITS;
#pragma unroll
    for (int u = 0; u < UNITS; u++) atomicAdd(&sums[base + u], y[u]);
#pragma unroll
    for (int u = 0; u < UNITS; u++) atomicMax(&maxu[base + u], fmap(y[u]));
}

// Pass 4: hybrid = sigmoid(alpha)*max + (1-sigmoid(alpha))*mean, in-place over sums
__global__ void __launch_bounds__(BLOCK) pillar_kernel(float* __restrict__ sums,
        const unsigned int* __restrict__ maxu, const int* __restrict__ cnt,
        const float* __restrict__ alpha, int total) {
    int idx = blockIdx.x * BLOCK + threadIdx.x;
    if (idx >= total) return;
    int p = idx >> 5;
    int n = cnt[p];
    float s = sums[idx];
    float m = (n > 0) ? funmap(maxu[idx]) : 0.f;
    float mean = s / fmaxf((float)n, 1.f);
    float a = 1.f / (1.f + expf(-alpha[0]));
    sums[idx] = a * m + (1.f - a) * mean;
}

// Pass 5: gather hybrid back into second half of each out row (8 float4/row)
__global__ void __launch_bounds__(BLOCK) gather_kernel(const float* __restrict__ hybrid,
        const int* __restrict__ unq, float* __restrict__ out, int total) {
    int gid = blockIdx.x * BLOCK + threadIdx.x;
    if (gid >= total) return;
    int row = gid >> 3, g = gid & 7;
    int p = unq[row];
    float4 h = ((const float4*)hybrid)[p * 8 + g];
    ((float4*)out)[(size_t)row * 16 + 8 + g] = h;
}

extern "C" void kernel_launch(void* const* d_in, const int* in_sizes, int n_in,
                              void* d_out, int out_size, void* d_ws, size_t ws_size,
                              hipStream_t stream) {
    const float* inp   = (const float*)d_in[0];
    const float* W     = (const float*)d_in[1];
    const float* gamma = (const float*)d_in[2];
    const float* beta  = (const float*)d_in[3];
    const float* pra   = (const float*)d_in[4];
    const float* alpha = (const float*)d_in[5];
    const int*   unq   = (const int*)d_in[6];
    int N = in_sizes[0] / IN_CH;
    float* out = (float*)d_out;

    char* ws = (char*)d_ws;
    float* partials    = (float*)ws;                    // 1024*64 f  = 262144 B
    float* params      = (float*)(ws + 262144);         // 64 f       = 256 B
    int*   cnt         = (int*)(ws + 262400);           // 30000*4    = 120000 B
    float* sums        = (float*)(ws + 382400);         // 960000*4   = 3840000 B
    unsigned int* maxu = (unsigned int*)(ws + 4222400); // 960000*4   = 3840000 B
    // total ws use: 8,062,400 B

    // zero cnt + sums + maxu (0 is the identity for the mapped-uint max too)
    hipMemsetAsync(ws + 262400, 0, 7800000, stream);

    hipLaunchKernelGGL(stats_kernel, dim3(STATS_BLOCKS), dim3(BLOCK), 0, stream,
                       inp, W, partials, N);
    hipLaunchKernelGGL(bn_finalize_kernel, dim3(1), dim3(BLOCK), 0, stream,
                       partials, gamma, beta, params, STATS_BLOCKS, 1.f / (float)N);
    hipLaunchKernelGGL(main_kernel, dim3((N + BLOCK - 1) / BLOCK), dim3(BLOCK), 0, stream,
                       inp, W, params, pra, unq, out, sums, maxu, cnt, N);
    int ptotal = PILLARS * UNITS;
    hipLaunchKernelGGL(pillar_kernel, dim3((ptotal + BLOCK - 1) / BLOCK), dim3(BLOCK), 0, stream,
                       sums, maxu, cnt, alpha, ptotal);
    int gtotal = N * 8;
    hipLaunchKernelGGL(gather_kernel, dim3((gtotal + BLOCK - 1) / BLOCK), dim3(BLOCK), 0, stream,
                       sums, unq, out, gtotal);
}